// Round 11
// baseline (68.895 us; speedup 1.0000x reference)
//
#include <hip/hip_runtime.h>
#include <hip/hip_bf16.h>

#define DIM 384
#define RED 16
#define PAIR 128
#define B 2
#define M 512
#define EPSV 1e-5f

typedef float f32x4 __attribute__((ext_vector_type(4)));
typedef short bf16x8 __attribute__((ext_vector_type(8)));

__device__ __forceinline__ unsigned short f2bf(float f) {
  union { float f; unsigned u; } v; v.f = f;
  unsigned r = v.u + 0x7fffu + ((v.u >> 16) & 1u);   // RTN-even
  return (unsigned short)(r >> 16);
}

// ---------------------------------------------------------------------------
// K1: 8 rows per block, 256 threads.
//  A: LN per wave (2 rows each, xor-butterfly)  -> xn_s[8][384]
//  B: xr: 32 thr/row (16 r x 2 halves of 192)   -> xr_s[8][16], xr_bf
//  C: T: thread (p=tid&127, rg=tid>>7) accumulates 4 rows at once,
//     each w_out element loaded once per thread -> T_bf[row][p][i] (bf16)
// grid = B*M/8 = 128 blocks
// ---------------------------------------------------------------------------
__global__ __launch_bounds__(256) void opm_k1(
    const float* __restrict__ x, const float* __restrict__ g,
    const float* __restrict__ be, const float* __restrict__ w_red,
    const float* __restrict__ b_red, const float* __restrict__ w_out,
    unsigned short* __restrict__ xr_bf, unsigned short* __restrict__ T_bf) {
  const int row0 = blockIdx.x * 8;
  const int tid  = threadIdx.x;
  const int wave = tid >> 6;            // 0..3
  const int lane = tid & 63;

  __shared__ float xn_s[8][DIM];        // 12 KB
  __shared__ float xr_s[8][RED];
  __shared__ float psum[8][2][RED];

  // ---- Phase A: LayerNorm, wave w -> rows 2w, 2w+1 ----
  #pragma unroll
  for (int rr = 0; rr < 2; ++rr) {
    const int rl = wave * 2 + rr;
    const float* xrow = x + (size_t)(row0 + rl) * DIM;
    float v[6];
    #pragma unroll
    for (int k = 0; k < 6; ++k) v[k] = xrow[lane + 64 * k];
    float s = 0.f, sq = 0.f;
    #pragma unroll
    for (int k = 0; k < 6; ++k) { s += v[k]; sq += v[k] * v[k]; }
    #pragma unroll
    for (int off = 32; off > 0; off >>= 1) {
      s  += __shfl_xor(s, off);
      sq += __shfl_xor(sq, off);
    }
    const float mean = s * (1.0f / DIM);
    const float var  = sq * (1.0f / DIM) - mean * mean;
    const float rstd = rsqrtf(var + EPSV);
    #pragma unroll
    for (int k = 0; k < 6; ++k) {
      const int d = lane + 64 * k;
      xn_s[rl][d] = (v[k] - mean) * rstd * g[d] + be[d];
    }
  }
  __syncthreads();

  // ---- Phase B: xr. 32 thr/row: r = t5&15, half = t5>>4 (2 x 192 dims) ----
  {
    const int r8 = tid >> 5, t5 = tid & 31;
    const int r = t5 & 15, half = t5 >> 4;
    const int d0 = half * 192;
    float ps = 0.f;
    #pragma unroll 4
    for (int d = d0; d < d0 + 192; ++d) ps += xn_s[r8][d] * w_red[d * RED + r];
    psum[r8][half][r] = ps;
  }
  __syncthreads();
  if (tid < 128) {
    const int r8 = tid >> 4, r = tid & 15;
    const float v = b_red[r] + psum[r8][0][r] + psum[r8][1][r];
    xr_s[r8][r] = v;
    xr_bf[(size_t)(row0 + r8) * RED + r] = f2bf(v);
  }
  __syncthreads();

  // ---- Phase C: T for 8 rows; each thread: 4 rows, each w element once ----
  {
    const int p  = tid & 127;
    const int rg = tid >> 7;            // 0,1 -> rows rg*4 .. rg*4+3
    const float* W = w_out + p;
    float xr0[RED], xr1[RED], xr2[RED], xr3[RED];
    #pragma unroll
    for (int j = 0; j < RED; ++j) {
      xr0[j] = xr_s[rg * 4 + 0][j];
      xr1[j] = xr_s[rg * 4 + 1][j];
      xr2[j] = xr_s[rg * 4 + 2][j];
      xr3[j] = xr_s[rg * 4 + 3][j];
    }
    #pragma unroll
    for (int i = 0; i < RED; i += 2) {
      float a0[4] = {0.f, 0.f, 0.f, 0.f};   // rows x {i, i+1}
      float a1[4] = {0.f, 0.f, 0.f, 0.f};
      #pragma unroll
      for (int j = 0; j < RED; ++j) {
        const float w0 = W[((i    ) * RED + j) * PAIR];
        const float w1 = W[((i + 1) * RED + j) * PAIR];
        a0[0] += xr0[j] * w0;  a1[0] += xr0[j] * w1;
        a0[1] += xr1[j] * w0;  a1[1] += xr1[j] * w1;
        a0[2] += xr2[j] * w0;  a1[2] += xr2[j] * w1;
        a0[3] += xr3[j] * w0;  a1[3] += xr3[j] * w1;
      }
      #pragma unroll
      for (int rr = 0; rr < 4; ++rr) {
        unsigned int* dst =
            (unsigned int*)(T_bf + ((size_t)(row0 + rg * 4 + rr) * PAIR + p) * RED);
        dst[i >> 1] = (unsigned)f2bf(a0[rr]) | ((unsigned)f2bf(a1[rr]) << 16);
      }
    }
  }
}

// ---------------------------------------------------------------------------
// K2 (round-8 champion, verbatim): MFMA swapped operands -> transposed D ->
// one dwordx4 store per MFMA.
//   out[b,m,n,p] = b_out[p] + sum_i T[b,n,i,p] * xr[b,m,i]
// One wave per n (4 n/block), K padded 16->32 (q<2 lanes hold data).
// tile = 64 m x 4 n x 128 p.  grid = B*(M/64)*(M/4) = 2048
// ---------------------------------------------------------------------------
__global__ __launch_bounds__(256) void opm_k2(
    const unsigned short* __restrict__ xr_bf, const unsigned short* __restrict__ T_bf,
    const float* __restrict__ b_out, float* __restrict__ out) {
  const int nb = blockIdx.x & 127;          // n-group (M/4 = 128)
  const int mt = (blockIdx.x >> 7) & 7;     // m-tile  (M/64 = 8)
  const int b  = blockIdx.x >> 10;
  const int wave = threadIdx.x >> 6;
  const int lane = threadIdx.x & 63;
  const int q = lane >> 4;                  // k-quad
  const int r = lane & 15;                  // A-row (p) / D-col (m)
  const int n = nb * 4 + wave;

  // A fragments (T): tv[pb] lane(q,r) holds T[n][i=8q..8q+7][pb*16+r]; q>=2 -> 0
  bf16x8 tv[8];
  const unsigned short* Tb = T_bf + ((size_t)(b * M + n) * PAIR) * RED;
  #pragma unroll
  for (int pb = 0; pb < 8; ++pb) {
    bf16x8 v = {0, 0, 0, 0, 0, 0, 0, 0};
    if (q < 2) v = *(const bf16x8*)(Tb + (pb * 16 + r) * RED + q * 8);
    tv[pb] = v;
  }
  // bias: 4 consecutive p per lane, per pb
  f32x4 biasv[8];
  #pragma unroll
  for (int pb = 0; pb < 8; ++pb)
    biasv[pb] = *(const f32x4*)(b_out + pb * 16 + q * 4);

  #pragma unroll
  for (int ms = 0; ms < 4; ++ms) {
    const int m0 = mt * 64 + ms * 16;
    // B fragment (xr): lane(q,r) holds xr[m0+r][8q..8q+7] as cols; q>=2 -> 0
    bf16x8 xv = {0, 0, 0, 0, 0, 0, 0, 0};
    if (q < 2) xv = *(const bf16x8*)(xr_bf + (size_t)(b * M + m0 + r) * RED + q * 8);

    // store base: (m = m0 + r, n), p = pb*16 + q*4
    float* ob = out + ((size_t)(b * M + m0 + r) * M + n) * PAIR + q * 4;
    #pragma unroll
    for (int pb = 0; pb < 8; ++pb) {
      f32x4 acc = biasv[pb];
      acc = __builtin_amdgcn_mfma_f32_16x16x32_bf16(tv[pb], xv, acc, 0, 0, 0);
      *(f32x4*)(ob + pb * 16) = acc;
    }
  }
}

extern "C" void kernel_launch(void* const* d_in, const int* in_sizes, int n_in,
                              void* d_out, int out_size, void* d_ws, size_t ws_size,
                              hipStream_t stream) {
  const float* x       = (const float*)d_in[0];
  const float* ln_g    = (const float*)d_in[1];
  const float* ln_b    = (const float*)d_in[2];
  const float* w_red   = (const float*)d_in[3];
  const float* b_red   = (const float*)d_in[4];
  const float* w_out   = (const float*)d_in[5];
  const float* b_out   = (const float*)d_in[6];
  float* out = (float*)d_out;

  unsigned short* xr_bf = (unsigned short*)d_ws;            // B*M*16 u16 = 32 KB
  unsigned short* T_bf  = xr_bf + (size_t)B * M * RED;      // B*M*128*16 u16 = 4 MB

  opm_k1<<<B * M / 8, 256, 0, stream>>>(x, ln_g, ln_b, w_red, b_red, w_out, xr_bf, T_bf);
  opm_k2<<<B * (M / 64) * (M / 4), 256, 0, stream>>>(xr_bf, T_bf, b_out, out);
}

// Round 12
// 56.941 us; speedup vs baseline: 1.2099x; 1.2099x over previous
//
#include <hip/hip_runtime.h>
#include <hip/hip_bf16.h>

#define DIM 384
#define RED 16
#define PAIR 128
#define B 2
#define M 512
#define EPSV 1e-5f

typedef float f32x4 __attribute__((ext_vector_type(4)));
typedef short bf16x8 __attribute__((ext_vector_type(8)));

__device__ __forceinline__ unsigned short f2bf(float f) {
  union { float f; unsigned u; } v; v.f = f;
  unsigned r = v.u + 0x7fffu + ((v.u >> 16) & 1u);   // RTN-even
  return (unsigned short)(r >> 16);
}

// ---------------------------------------------------------------------------
// K1 (round-5/8 proven version): per (b,m) row: LayerNorm(384) -> xr[16] (bf16)
//     -> T_bf[row][p][i] = bf16( sum_j xr[j] * w_out[(i*16+j)*128 + p] )
// grid = B*M = 1024 blocks, block = 128 threads
// ---------------------------------------------------------------------------
__global__ __launch_bounds__(128) void opm_k1(
    const float* __restrict__ x, const float* __restrict__ g,
    const float* __restrict__ be, const float* __restrict__ w_red,
    const float* __restrict__ b_red, const float* __restrict__ w_out,
    unsigned short* __restrict__ xr_bf, unsigned short* __restrict__ T_bf) {
  const int row = blockIdx.x;           // b*M + m
  const int tid = threadIdx.x;          // 0..127
  const float* xrow = x + (size_t)row * DIM;

  __shared__ float xn[DIM];
  __shared__ float xr_s[RED];
  __shared__ float rs[2][2];
  __shared__ float psum[8][RED];

  float v0 = xrow[tid];
  float v1 = xrow[tid + 128];
  float v2 = xrow[tid + 256];
  float s  = v0 + v1 + v2;
  float sq = v0 * v0 + v1 * v1 + v2 * v2;
  #pragma unroll
  for (int off = 32; off > 0; off >>= 1) {
    s  += __shfl_down(s, off);
    sq += __shfl_down(sq, off);
  }
  if ((tid & 63) == 0) { rs[0][tid >> 6] = s; rs[1][tid >> 6] = sq; }
  __syncthreads();
  const float mean = (rs[0][0] + rs[0][1]) * (1.0f / DIM);
  const float var  = (rs[1][0] + rs[1][1]) * (1.0f / DIM) - mean * mean;
  const float rstd = rsqrtf(var + EPSV);

  xn[tid]       = (v0 - mean) * rstd * g[tid]       + be[tid];
  xn[tid + 128] = (v1 - mean) * rstd * g[tid + 128] + be[tid + 128];
  xn[tid + 256] = (v2 - mean) * rstd * g[tid + 256] + be[tid + 256];
  __syncthreads();

  {
    const int r = tid & 15;
    const int part = tid >> 4;  // 0..7
    float ps = 0.0f;
    const int d0 = part * 48;
    #pragma unroll 8
    for (int d = d0; d < d0 + 48; ++d) ps += xn[d] * w_red[d * RED + r];
    psum[part][r] = ps;
  }
  __syncthreads();
  if (tid < RED) {
    float v = b_red[tid];
    #pragma unroll
    for (int q = 0; q < 8; ++q) v += psum[q][tid];
    xr_s[tid] = v;
    xr_bf[(size_t)row * RED + tid] = f2bf(v);
  }
  __syncthreads();

  // T row, layout [p][i] (i contiguous), bf16
  {
    const int p = tid;  // 0..127
    const float* W = w_out + p;
    float acc[RED];
    #pragma unroll
    for (int i = 0; i < RED; ++i) {
      float a = 0.0f;
      #pragma unroll
      for (int j = 0; j < RED; ++j) a += xr_s[j] * W[(i * RED + j) * PAIR];
      acc[i] = a;
    }
    unsigned int w0[4], w1[4];
    #pragma unroll
    for (int k = 0; k < 4; ++k) {
      w0[k] = (unsigned)f2bf(acc[2*k])     | ((unsigned)f2bf(acc[2*k+1]) << 16);
      w1[k] = (unsigned)f2bf(acc[8+2*k])   | ((unsigned)f2bf(acc[8+2*k+1]) << 16);
    }
    unsigned int* dst = (unsigned int*)(T_bf + ((size_t)row * PAIR + p) * RED);
    #pragma unroll
    for (int k = 0; k < 4; ++k) { dst[k] = w0[k]; dst[4+k] = w1[k]; }
  }
}

// ---------------------------------------------------------------------------
// K2 (MFMA, SWAPPED operands -> transposed D -> dwordx4 stores):
//   out[b,m,n,p] = b_out[p] + sum_i T[b,n,i,p] * xr[b,m,i]
// D = A*B with A = T-frag (rows = p), B = xr (cols = m):
//   lane(q=lane>>4, r=lane&15): D col = r = m_loc, rows = q*4+reg = p_loc
//   -> acc[0..3] = 4 consecutive p at fixed (m,n): ONE dwordx4 store per MFMA.
// One wave per n (4 n/block), K padded 16->32 (q<2 lanes hold data).
// tile = 64 m x 4 n x 128 p.  grid = B*(M/64)*(M/4) = 2048
// ---------------------------------------------------------------------------
__global__ __launch_bounds__(256) void opm_k2(
    const unsigned short* __restrict__ xr_bf, const unsigned short* __restrict__ T_bf,
    const float* __restrict__ b_out, float* __restrict__ out) {
  const int nb = blockIdx.x & 127;          // n-group (M/4 = 128)
  const int mt = (blockIdx.x >> 7) & 7;     // m-tile  (M/64 = 8)
  const int b  = blockIdx.x >> 10;
  const int wave = threadIdx.x >> 6;
  const int lane = threadIdx.x & 63;
  const int q = lane >> 4;                  // k-quad
  const int r = lane & 15;                  // A-row (p) / D-col (m)
  const int n = nb * 4 + wave;

  // A fragments (T): tv[pb] lane(q,r) holds T[n][i=8q..8q+7][pb*16+r]; q>=2 -> 0
  bf16x8 tv[8];
  const unsigned short* Tb = T_bf + ((size_t)(b * M + n) * PAIR) * RED;
  #pragma unroll
  for (int pb = 0; pb < 8; ++pb) {
    bf16x8 v = {0, 0, 0, 0, 0, 0, 0, 0};
    if (q < 2) v = *(const bf16x8*)(Tb + (pb * 16 + r) * RED + q * 8);
    tv[pb] = v;
  }
  // bias: 4 consecutive p per lane, per pb
  f32x4 biasv[8];
  #pragma unroll
  for (int pb = 0; pb < 8; ++pb)
    biasv[pb] = *(const f32x4*)(b_out + pb * 16 + q * 4);

  #pragma unroll
  for (int ms = 0; ms < 4; ++ms) {
    const int m0 = mt * 64 + ms * 16;
    // B fragment (xr): lane(q,r) holds xr[m0+r][8q..8q+7] as cols; q>=2 -> 0
    bf16x8 xv = {0, 0, 0, 0, 0, 0, 0, 0};
    if (q < 2) xv = *(const bf16x8*)(xr_bf + (size_t)(b * M + m0 + r) * RED + q * 8);

    // store base: (m = m0 + r, n), p = pb*16 + q*4
    float* ob = out + ((size_t)(b * M + m0 + r) * M + n) * PAIR + q * 4;
    #pragma unroll
    for (int pb = 0; pb < 8; ++pb) {
      f32x4 acc = biasv[pb];
      acc = __builtin_amdgcn_mfma_f32_16x16x32_bf16(tv[pb], xv, acc, 0, 0, 0);
      *(f32x4*)(ob + pb * 16) = acc;
    }
  }
}

extern "C" void kernel_launch(void* const* d_in, const int* in_sizes, int n_in,
                              void* d_out, int out_size, void* d_ws, size_t ws_size,
                              hipStream_t stream) {
  const float* x       = (const float*)d_in[0];
  const float* ln_g    = (const float*)d_in[1];
  const float* ln_b    = (const float*)d_in[2];
  const float* w_red   = (const float*)d_in[3];
  const float* b_red   = (const float*)d_in[4];
  const float* w_out   = (const float*)d_in[5];
  const float* b_out   = (const float*)d_in[6];
  float* out = (float*)d_out;

  unsigned short* xr_bf = (unsigned short*)d_ws;            // B*M*16 u16 = 32 KB
  unsigned short* T_bf  = xr_bf + (size_t)B * M * RED;      // B*M*128*16 u16 = 4 MB

  opm_k1<<<B * M, 128, 0, stream>>>(x, ln_g, ln_b, w_red, b_red, w_out, xr_bf, T_bf);
  opm_k2<<<B * (M / 64) * (M / 4), 256, 0, stream>>>(xr_bf, T_bf, b_out, out);
}